// Round 1
// baseline (83.490 us; speedup 1.0000x reference)
//
#include <hip/hip_runtime.h>

// Problem constants (from reference setup_inputs)
static constexpr int kA = 128;   // atoms
static constexpr int kN = 64;    // neighbors
static constexpr int kG = 16;    // grid size per axis
static constexpr int kC = 10;    // channels = 5 types x 2 grid lengths

// out[b=0][a][c][x][y][z], c = type_idx*2 + length_idx
// Per channel (Z, L):
//   out = sum_{n: Z_n == Z} exp(coeff*||g - d_n||^2) + (N - cnt_Z) * exp(coeff*|g|^2)
// because the reference masks d (not the exp), so non-matching neighbors
// contribute an origin-centered Gaussian.
// Separable: exp(coeff*||g-d||^2) = ex[x]*ey[y]*ez[z].

__global__ __launch_bounds__(256) void voxel_kernel(
    const float* __restrict__ dvec,   // (1, A, N, 3) fp32
    const float* __restrict__ sigma,  // (1,) fp32
    const int*   __restrict__ zn,     // (A, N) int32
    float*       __restrict__ out)    // (1, A, 10, G, G, G) fp32
{
    const int blk = blockIdx.x;       // a*2 + li
    const int a   = blk >> 1;
    const int li  = blk & 1;
    const float Lg   = li ? 12.0f : 8.0f;
    const float step = Lg * (1.0f / 15.0f);
    const float t0   = -0.5f * Lg;
    const float sg   = sigma[0];
    const float coeff = -0.5f / (sg * sg);

    const int t = threadIdx.x;        // 0..255
    const int x = t >> 4;
    const int y = t & 15;
    const float gx = t0 + x * step;
    const float gy = t0 + y * step;

    __shared__ float s_ex[kN * kG];   // ex[n][i] = exp(coeff*(tick[i]-dx_n)^2)
    __shared__ float s_ey[kN * kG];
    __shared__ float s_ez[kN * kG];
    __shared__ int   s_ch[kN];        // channel index per neighbor, -1 if type unlisted

    // Classify neighbors by atom type (Z in {1,6,7,8,16} -> ch 0..4, else -1)
    if (t < kN) {
        int Z = zn[a * kN + t];
        int ch = -1;
        if      (Z == 1)  ch = 0;
        else if (Z == 6)  ch = 1;
        else if (Z == 7)  ch = 2;
        else if (Z == 8)  ch = 3;
        else if (Z == 16) ch = 4;
        s_ch[t] = ch;
    }

    // Precompute separable Gaussian factors: 64 neighbors x 16 ticks x 3 axes
    for (int idx = t; idx < kN * kG; idx += 256) {
        const int n = idx >> 4;
        const int i = idx & 15;
        const float tick = t0 + i * step;
        const float* dv = dvec + (size_t)(a * kN + n) * 3;
        const float dx = tick - dv[0];
        const float dy = tick - dv[1];
        const float dz = tick - dv[2];
        s_ex[idx] = __expf(coeff * dx * dx);
        s_ey[idx] = __expf(coeff * dy * dy);
        s_ez[idx] = __expf(coeff * dz * dz);
    }
    __syncthreads();

    // Origin-centered Gaussian along this thread's z-line
    float e0z[kG];
#pragma unroll
    for (int z = 0; z < kG; ++z) {
        const float gz = t0 + z * step;
        e0z[z] = __expf(coeff * gz * gz);
    }
    const float p0 = __expf(coeff * gx * gx) * __expf(coeff * gy * gy);

    // Channel-major accumulation: static register indexing, wave-uniform branch
    for (int ch = 0; ch < 5; ++ch) {
        float acc[kG];
#pragma unroll
        for (int z = 0; z < kG; ++z) acc[z] = 0.0f;

        int cnt = 0;
        for (int n = 0; n < kN; ++n) {
            if (s_ch[n] == ch) {          // wave-uniform (same for all lanes)
                ++cnt;
                const float p = s_ex[n * kG + x] * s_ey[n * kG + y];
#pragma unroll
                for (int z = 0; z < kG; ++z)
                    acc[z] = fmaf(p, s_ez[n * kG + z], acc[z]);
            }
        }

        // Non-matching neighbors each contribute the origin Gaussian
        const float w = (float)(kN - cnt) * p0;
#pragma unroll
        for (int z = 0; z < kG; ++z)
            acc[z] = fmaf(w, e0z[z], acc[z]);

        // Coalesced store: thread t writes 16 consecutive floats (its z-line)
        float4* o = (float4*)(out + (((size_t)a * kC + ch * 2 + li) * (kG * kG * kG)
                                     + (size_t)t * kG));
#pragma unroll
        for (int q = 0; q < 4; ++q)
            o[q] = make_float4(acc[q * 4 + 0], acc[q * 4 + 1],
                               acc[q * 4 + 2], acc[q * 4 + 3]);
    }
}

extern "C" void kernel_launch(void* const* d_in, const int* in_sizes, int n_in,
                              void* d_out, int out_size, void* d_ws, size_t ws_size,
                              hipStream_t stream) {
    const float* dvec  = (const float*)d_in[0];   // distance_vector (1,128,64,3) fp32
    const float* sigma = (const float*)d_in[1];   // sigma (1,) fp32
    const int*   zn    = (const int*)d_in[2];     // atomic_numbers (128,64) int32
    float* out = (float*)d_out;                   // (1,128,10,16,16,16) fp32

    voxel_kernel<<<dim3(kA * 2), dim3(256), 0, stream>>>(dvec, sigma, zn, out);
}

// Round 2
// 70.395 us; speedup vs baseline: 1.1860x; 1.1860x over previous
//
#include <hip/hip_runtime.h>

// Problem constants (from reference setup_inputs)
static constexpr int kA = 128;   // atoms
static constexpr int kN = 64;    // neighbors
static constexpr int kG = 16;    // grid size per axis
static constexpr int kC = 10;    // channels = 5 types x 2 grid lengths

// out[b=0][a][c][x][y][z], c = type_idx*2 + length_idx
// Per channel (Z, L):
//   out = sum_{n: Z_n == Z} exp(coeff*||g - d_n||^2) + (N - cnt_Z) * exp(coeff*|g|^2)
// (reference masks d, not the exp, so non-matching neighbors contribute an
//  origin-centered Gaussian). Separable: exp(coeff*||g-d||^2) = ex*ey*ez.
//
// Decomposition: 1 block per (a, type, L) = 1280 blocks -> ~5 blocks/CU.
// Neighbor classification via wave-wide __ballot (64-bit mask in SGPRs) —
// no dependent-LDS scan. Thread t owns grid column (x=t>>4, y=t&15), 16 z
// voxels in registers.

__global__ __launch_bounds__(256) void voxel_kernel(
    const float* __restrict__ dvec,   // (1, A, N, 3) fp32
    const float* __restrict__ sigma,  // (1,) fp32
    const int*   __restrict__ zn,     // (A, N) int32
    float*       __restrict__ out)    // (1, A, 10, G, G, G) fp32
{
    const int blk = blockIdx.x;          // a*10 + c,  c = ch*2 + li
    const int a   = blk / 10;
    const int c   = blk - a * 10;
    const int ch  = c >> 1;
    const int li  = c & 1;

    const int Ztab[5] = {1, 6, 7, 8, 16};
    const int Ztarget = Ztab[ch];

    const float Lg   = li ? 12.0f : 8.0f;
    const float step = Lg * (1.0f / 15.0f);
    const float t0   = -0.5f * Lg;
    const float sg   = sigma[0];
    const float coeff = -0.5f / (sg * sg);

    const int t = threadIdx.x;           // 0..255
    const int x = t >> 4;
    const int y = t & 15;
    const float gx = t0 + x * step;
    const float gy = t0 + y * step;

    __shared__ int   s_idx[kN];          // compacted matching-neighbor indices
    __shared__ float s_ez[kN * kG];      // ez[j][z] for matching neighbor j

    // --- Classification: every wave loads the same 64 zn values and ballots.
    const int lane = t & 63;
    const int Zl   = zn[a * kN + lane];
    const bool match = (Zl == Ztarget);
    const unsigned long long mask = __ballot(match);
    const int cnt = __popcll(mask);      // wave-uniform, identical in all waves

    // Wave 0 writes the compacted index list (position = rank within mask).
    if (t < 64 && match) {
        const int pos = __popcll(mask & ((1ull << lane) - 1ull));
        s_idx[pos] = lane;
    }
    __syncthreads();

    // --- Stage ez table for matching neighbors: cnt*16 entries.
    for (int idx = t; idx < cnt * kG; idx += 256) {
        const int j  = idx >> 4;
        const int zz = idx & 15;
        const int n  = s_idx[j];
        const float dz = dvec[((size_t)(a * kN + n)) * 3 + 2];
        const float gz = t0 + zz * step;
        const float r  = gz - dz;
        s_ez[idx] = __expf(coeff * r * r);
    }
    __syncthreads();

    // --- Origin-centered term: (kN - cnt) neighbors contribute gauss(0).
    float acc[kG];
    {
        const float w = (float)(kN - cnt) * __expf(coeff * (gx * gx + gy * gy));
#pragma unroll
        for (int z = 0; z < kG; ++z) {
            const float gz = t0 + z * step;
            acc[z] = w * __expf(coeff * gz * gz);
        }
    }

    // --- Matching neighbors: 2 exps + 16 FMA each (ez via LDS broadcast).
    for (int j = 0; j < cnt; ++j) {
        const int n = __builtin_amdgcn_readfirstlane(s_idx[j]);  // force scalar
        const float dx = dvec[((size_t)(a * kN + n)) * 3 + 0];
        const float dy = dvec[((size_t)(a * kN + n)) * 3 + 1];
        const float rx = gx - dx;
        const float ry = gy - dy;
        const float p  = __expf(coeff * (rx * rx + ry * ry));
#pragma unroll
        for (int z = 0; z < kG; ++z)
            acc[z] = fmaf(p, s_ez[j * kG + z], acc[z]);
    }

    // --- Coalesced store: thread t writes its 16-float z-line.
    float4* o = (float4*)(out + ((size_t)a * kC + c) * (kG * kG * kG)
                              + (size_t)t * kG);
#pragma unroll
    for (int q = 0; q < 4; ++q)
        o[q] = make_float4(acc[q * 4 + 0], acc[q * 4 + 1],
                           acc[q * 4 + 2], acc[q * 4 + 3]);
}

extern "C" void kernel_launch(void* const* d_in, const int* in_sizes, int n_in,
                              void* d_out, int out_size, void* d_ws, size_t ws_size,
                              hipStream_t stream) {
    const float* dvec  = (const float*)d_in[0];   // distance_vector (1,128,64,3) fp32
    const float* sigma = (const float*)d_in[1];   // sigma (1,) fp32
    const int*   zn    = (const int*)d_in[2];     // atomic_numbers (128,64) int32
    float* out = (float*)d_out;                   // (1,128,10,16,16,16) fp32

    voxel_kernel<<<dim3(kA * kC), dim3(256), 0, stream>>>(dvec, sigma, zn, out);
}

// Round 3
// 69.588 us; speedup vs baseline: 1.1998x; 1.0116x over previous
//
#include <hip/hip_runtime.h>

// Problem constants (from reference setup_inputs)
static constexpr int kA = 128;   // atoms
static constexpr int kN = 64;    // neighbors
static constexpr int kG = 16;    // grid size per axis
static constexpr int kC = 10;    // channels = 5 types x 2 grid lengths

// out[b=0][a][c][x][y][z], c = type_idx*2 + length_idx
// Per channel (Z, L):
//   out = sum_{n: Z_n == Z} exp(coeff*||g - d_n||^2) + (N - cnt_Z) * exp(coeff*|g|^2)
// (reference masks d, not the exp, so non-matching neighbors contribute an
//  origin-centered Gaussian). Separable: exp(coeff*||g-d||^2) = ex*ey*ez.
//
// Round-3 structure: 1 block per (a, type, L) = 1280 blocks (~5/CU).
//  - Prologue stages ex/ey/ez for ALL 64 neighbors (12 KB LDS) from ONE
//    coalesced 768 B dvec read; classification is a per-wave __ballot with
//    the matched set iterated as SGPR mask bits (ctz). ONE __syncthreads.
//  - Hot loop: no global loads, no exps, no dependent index loads —
//    2 broadcast LDS reads + 4 uniform ds_read_b128 + 16 FMA per neighbor.

__global__ __launch_bounds__(256) void voxel_kernel(
    const float* __restrict__ dvec,   // (1, A, N, 3) fp32
    const float* __restrict__ sigma,  // (1,) fp32
    const int*   __restrict__ zn,     // (A, N) int32
    float*       __restrict__ out)    // (1, A, 10, G, G, G) fp32
{
    const int blk = blockIdx.x;          // a*10 + c,  c = ch*2 + li
    const int a   = blk / 10;
    const int c   = blk - a * 10;
    const int ch  = c >> 1;
    const int li  = c & 1;

    const int Ztab[5] = {1, 6, 7, 8, 16};
    const int Ztarget = Ztab[ch];

    const float Lg   = li ? 12.0f : 8.0f;
    const float step = Lg * (1.0f / 15.0f);
    const float t0   = -0.5f * Lg;
    const float sg   = sigma[0];
    const float coeff = -0.5f / (sg * sg);

    const int t = threadIdx.x;           // 0..255
    const int x = t >> 4;
    const int y = t & 15;

    __shared__ float s_tab[3 * kN * kG]; // [axis][n][tick], 12 KB

    // --- Stage separable tables: thread t<192 owns flat dvec element t
    //     (layout (N,3): n = t/3, axis = t%3) — one coalesced 768 B read.
    if (t < 192) {
        const float d  = dvec[(size_t)a * (kN * 3) + t];
        const int   n  = t / 3;
        const int   ax = t - 3 * n;
        float* dst = &s_tab[(ax * kN + n) * kG];
#pragma unroll
        for (int i = 0; i < kG; ++i) {
            const float r = (t0 + i * step) - d;
            dst[i] = __expf(coeff * r * r);
        }
    }

    // --- Classification: per-wave ballot, mask lives in SGPRs (identical in
    //     every wave — all load the same 64 zn values).
    const int lane = t & 63;
    const int Zl   = zn[a * kN + lane];
    unsigned long long mask = __ballot(Zl == Ztarget);
    const int cnt = __popcll(mask);

    __syncthreads();

    const float gx = t0 + x * step;
    const float gy = t0 + y * step;

    // --- Origin-centered term: (kN - cnt) non-matching neighbors.
    float acc[kG];
    {
        const float w = (float)(kN - cnt) * __expf(coeff * (gx * gx + gy * gy));
#pragma unroll
        for (int z = 0; z < kG; ++z) {
            const float gz = t0 + z * step;
            acc[z] = w * __expf(coeff * gz * gz);
        }
    }

    const float* s_ex = &s_tab[0 * kN * kG];
    const float* s_ey = &s_tab[1 * kN * kG];
    const float* s_ez = &s_tab[2 * kN * kG];

    // --- Matched neighbors: iterate set bits of the SGPR mask.
    while (mask) {
        const int n = (int)__builtin_ctzll(mask);   // wave-uniform (SGPR)
        mask &= mask - 1ull;
        const float p = s_ex[n * kG + x] * s_ey[n * kG + y];
#pragma unroll
        for (int z = 0; z < kG; ++z)
            acc[z] = fmaf(p, s_ez[n * kG + z], acc[z]);
    }

    // --- Coalesced store: thread t writes its 16-float z-line.
    float4* o = (float4*)(out + ((size_t)a * kC + c) * (kG * kG * kG)
                              + (size_t)t * kG);
#pragma unroll
    for (int q = 0; q < 4; ++q)
        o[q] = make_float4(acc[q * 4 + 0], acc[q * 4 + 1],
                           acc[q * 4 + 2], acc[q * 4 + 3]);
}

extern "C" void kernel_launch(void* const* d_in, const int* in_sizes, int n_in,
                              void* d_out, int out_size, void* d_ws, size_t ws_size,
                              hipStream_t stream) {
    const float* dvec  = (const float*)d_in[0];   // distance_vector (1,128,64,3) fp32
    const float* sigma = (const float*)d_in[1];   // sigma (1,) fp32
    const int*   zn    = (const int*)d_in[2];     // atomic_numbers (128,64) int32
    float* out = (float*)d_out;                   // (1,128,10,16,16,16) fp32

    voxel_kernel<<<dim3(kA * kC), dim3(256), 0, stream>>>(dvec, sigma, zn, out);
}

// Round 4
// 65.523 us; speedup vs baseline: 1.2742x; 1.0620x over previous
//
#include <hip/hip_runtime.h>

// Problem constants (from reference setup_inputs)
static constexpr int kA = 128;   // atoms
static constexpr int kN = 64;    // neighbors
static constexpr int kG = 16;    // grid size per axis
static constexpr int kC = 10;    // channels = 5 types x 2 grid lengths

// out[b=0][a][c][x][y][z], c = type_idx*2 + length_idx
// Per channel (Z, L):
//   out = sum_{n: Z_n == Z} exp(coeff*||g - d_n||^2) + (N - cnt_Z) * exp(coeff*|g|^2)
// (reference masks d, not the exp). Separable: exp = ex*ey*ez.
//
// Round-4: fully-coalesced stores. Thread t owns float4s #t,+256,+512,+768 of
// its channel (contiguous 1 KB per wave-instruction, full 64 B lines) instead
// of a private 64 B z-line (which made every store instruction touch 64
// distinct cache lines with 16 B partial writes — 4x write transactions).
// Ownership: y=(t>>2)&15 (16 lanes/wave groups), zq=t&3 (float4 along z),
// x = t>>6 + {0,4,8,12}  -> s_ex reads are WAVE-UNIFORM (x-base = wave id).
// Origin-term exps now come from a 16-entry LDS table (s_e0), not 17
// per-thread exps.

__global__ __launch_bounds__(256) void voxel_kernel(
    const float* __restrict__ dvec,   // (1, A, N, 3) fp32
    const float* __restrict__ sigma,  // (1,) fp32
    const int*   __restrict__ zn,     // (A, N) int32
    float*       __restrict__ out)    // (1, A, 10, G, G, G) fp32
{
    const int blk = blockIdx.x;          // a*10 + c,  c = ch*2 + li
    const int a   = blk / 10;
    const int c   = blk - a * 10;
    const int ch  = c >> 1;
    const int li  = c & 1;

    const int Ztab[5] = {1, 6, 7, 8, 16};
    const int Ztarget = Ztab[ch];

    const float Lg   = li ? 12.0f : 8.0f;
    const float step = Lg * (1.0f / 15.0f);
    const float t0   = -0.5f * Lg;
    const float sg   = sigma[0];
    const float coeff = -0.5f / (sg * sg);

    const int t = threadIdx.x;           // 0..255

    __shared__ float s_tab[3 * kN * kG]; // [axis][n][tick], 12 KB
    __shared__ float s_e0[kG];           // exp(coeff*tick^2)

    // --- Stage separable tables: thread t<192 owns flat dvec element t
    //     (layout (N,3): n = t/3, axis = t%3) — one coalesced 768 B read.
    if (t < 192) {
        const float d  = dvec[(size_t)a * (kN * 3) + t];
        const int   n  = t / 3;
        const int   ax = t - 3 * n;
        float* dst = &s_tab[(ax * kN + n) * kG];
#pragma unroll
        for (int i = 0; i < kG; ++i) {
            const float r = (t0 + i * step) - d;
            dst[i] = __expf(coeff * r * r);
        }
    } else if (t < 192 + kG) {
        const int i = t - 192;
        const float r = t0 + i * step;
        s_e0[i] = __expf(coeff * r * r);
    }

    // --- Classification: per-wave ballot; mask identical in every wave.
    const int lane = t & 63;
    const int Zl   = zn[a * kN + lane];
    unsigned long long mask = __ballot(Zl == Ztarget);
    const int cnt = __popcll(mask);

    __syncthreads();

    // Ownership mapping (see header): float4 #(t + 256q) = (x=t>>6+4q,
    // y=(t>>2)&15, z=4*(t&3)..+3).
    const int y  = (t >> 2) & 15;
    const int zq = (t & 3) * 4;
    const int xb = t >> 6;               // wave id; x_i = xb + 4i

    const float* s_ex = &s_tab[0 * kN * kG];
    const float* s_ey = &s_tab[1 * kN * kG];
    const float* s_ez = &s_tab[2 * kN * kG];

    // --- Origin-centered term via the s_e0 table.
    float acc[4][4];
    {
        const float w  = (float)(kN - cnt) * s_e0[y];
        float ez0[4];
#pragma unroll
        for (int j = 0; j < 4; ++j) ez0[j] = s_e0[zq + j];
#pragma unroll
        for (int i = 0; i < 4; ++i) {
            const float wx = w * s_e0[xb + 4 * i];
#pragma unroll
            for (int j = 0; j < 4; ++j)
                acc[i][j] = wx * ez0[j];
        }
    }

    // --- Matched neighbors: iterate set bits of the SGPR mask.
    while (mask) {
        const int n = (int)__builtin_ctzll(mask);   // wave-uniform
        mask &= mask - 1ull;
        const float eyn = s_ey[n * kG + y];
        float ezn[4];
#pragma unroll
        for (int j = 0; j < 4; ++j) ezn[j] = s_ez[n * kG + zq + j];
#pragma unroll
        for (int i = 0; i < 4; ++i) {
            const float p = s_ex[n * kG + xb + 4 * i] * eyn;  // s_ex wave-uniform
#pragma unroll
            for (int j = 0; j < 4; ++j)
                acc[i][j] = fmaf(p, ezn[j], acc[i][j]);
        }
    }

    // --- Fully-coalesced store: per instruction q, lane l writes float4
    //     #(wave*64 + l + 256q) — contiguous 1 KB per wave, full lines.
    float4* o = (float4*)(out + ((size_t)a * kC + c) * (kG * kG * kG));
#pragma unroll
    for (int q = 0; q < 4; ++q)
        o[t + 256 * q] = make_float4(acc[q][0], acc[q][1], acc[q][2], acc[q][3]);
}

extern "C" void kernel_launch(void* const* d_in, const int* in_sizes, int n_in,
                              void* d_out, int out_size, void* d_ws, size_t ws_size,
                              hipStream_t stream) {
    const float* dvec  = (const float*)d_in[0];   // distance_vector (1,128,64,3) fp32
    const float* sigma = (const float*)d_in[1];   // sigma (1,) fp32
    const int*   zn    = (const int*)d_in[2];     // atomic_numbers (128,64) int32
    float* out = (float*)d_out;                   // (1,128,10,16,16,16) fp32

    voxel_kernel<<<dim3(kA * kC), dim3(256), 0, stream>>>(dvec, sigma, zn, out);
}